// Round 20
// baseline (192.640 us; speedup 1.0000x reference)
//
#include <hip/hip_runtime.h>

// Problem constants (match reference)
#define Vv 4
#define Bn 2
#define Cn 32
#define Hn 128
#define Wn 128
#define Dn 32
#define Gn 8
#define Nn 4
// derived
#define HW (Hn*Wn)            // 16384
#define BHW (Bn*Hn*Wn)        // 32768
#define DHW (Dn*Hn*Wn)        // 524288
#define BDHW (Bn*Dn*Hn*Wn)    // 1048576
#define NBLK (DHW/256)        // 2048 blocks per warp stage (1-bin mapping)
#define WBLK (DHW/512)        // 1024 blocks per warp stage (2-bin mapping)
#define RBLK (Gn*HW/256)      // 512 repack blocks per stage
#define SBLK (BDHW/256)       // 4096 sample blocks
#define NST  (Vv*Bn)          // 8 stages

// ---------------------------------------------------------------------------
// setup: per (v,b) P = src_proj_new @ inv(ref_proj_new) in f64, plus
// wtab[0..7]=w_reg, wtab[8+k]=u1[k], wtab[40+k]=u2[k]
// ---------------------------------------------------------------------------
__global__ void setup_proj(const float* __restrict__ pm,
                           const float* __restrict__ wenh,
                           const float* __restrict__ wreg,
                           double* __restrict__ projws,
                           double* __restrict__ wtab) {
    int t = threadIdx.x;
    if (t < Gn) wtab[t] = (double)wreg[t];
    if (t < Gn * Nn) {
        double a = 0.0, c = 0.0;
        for (int g = 0; g < Gn; g++) {
            double wv = (double)wenh[g * (Gn * Nn) + t];
            a += wv;
            c += (double)wreg[g] * wv;
        }
        wtab[8 + t] = a; wtab[40 + t] = c;
    }
    if (t >= Vv * Bn) return;
    int v = t / Bn, b = t % Bn;
    const float* Eref = pm + (((size_t)b * (Vv + 1) + 0) * 2 + 0) * 16;
    const float* Kref = pm + (((size_t)b * (Vv + 1) + 0) * 2 + 1) * 16;
    const float* Esrc = pm + (((size_t)b * (Vv + 1) + (v + 1)) * 2 + 0) * 16;
    const float* Ksrc = pm + (((size_t)b * (Vv + 1) + (v + 1)) * 2 + 1) * 16;
    double R[16], S[16];
    for (int r = 0; r < 3; r++)
        for (int c = 0; c < 4; c++) {
            R[r*4+c] = (double)Kref[r*4+0]*Eref[0*4+c] + (double)Kref[r*4+1]*Eref[1*4+c] + (double)Kref[r*4+2]*Eref[2*4+c];
            S[r*4+c] = (double)Ksrc[r*4+0]*Esrc[0*4+c] + (double)Ksrc[r*4+1]*Esrc[1*4+c] + (double)Ksrc[r*4+2]*Esrc[2*4+c];
        }
    for (int c = 0; c < 4; c++) { R[12+c] = Eref[12+c]; S[12+c] = Esrc[12+c]; }
    double M[4][8];
    for (int r = 0; r < 4; r++)
        for (int c = 0; c < 4; c++) { M[r][c] = R[r*4+c]; M[r][4+c] = (r == c) ? 1.0 : 0.0; }
    for (int col = 0; col < 4; col++) {
        int piv = col; double best = fabs(M[col][col]);
        for (int r = col+1; r < 4; r++) { double a = fabs(M[r][col]); if (a > best) { best = a; piv = r; } }
        if (piv != col)
            for (int c = 0; c < 8; c++) { double tmp = M[col][c]; M[col][c] = M[piv][c]; M[piv][c] = tmp; }
        double inv = 1.0 / M[col][col];
        for (int c = 0; c < 8; c++) M[col][c] *= inv;
        for (int r = 0; r < 4; r++) if (r != col) {
            double f = M[r][col];
            for (int c = 0; c < 8; c++) M[r][c] -= f * M[col][c];
        }
    }
    double P[16];
    for (int r = 0; r < 4; r++)
        for (int c = 0; c < 4; c++) {
            double acc = 0.0;
            for (int k = 0; k < 4; k++) acc += S[r*4+k] * M[k][4+c];
            P[r*4+c] = acc;
        }
    double* o = projws + t * 12;
    o[0]=P[0];  o[1]=P[1];  o[2]=P[2];
    o[3]=P[4];  o[4]=P[5];  o[5]=P[6];
    o[6]=P[8];  o[7]=P[9];  o[8]=P[10];
    o[9]=P[3];  o[10]=P[7]; o[11]=P[11];
}

// ---------------------------------------------------------------------------
// depth transpose: dh [b][d][p] -> dhT [b][p][d] (32x32 tiles via LDS)
// ---------------------------------------------------------------------------
__global__ __launch_bounds__(256) void transpose_depth(
    const float* __restrict__ in, float* __restrict__ outT)
{
    __shared__ float tile[32][33];
    int b = blockIdx.y;
    int tx = threadIdx.x, ty = threadIdx.y;
    int p0 = blockIdx.x * 32;
    const float* ib = in + (size_t)b * DHW;
    float* ob = outT + (size_t)b * DHW;
    #pragma unroll
    for (int r = ty; r < 32; r += 8)
        tile[tx][r] = ib[(size_t)r * HW + p0 + tx];
    __syncthreads();
    #pragma unroll
    for (int r = ty; r < 32; r += 8)
        ob[(size_t)(p0 + r) * 32 + tx] = tile[r][tx];
}

// ---------------------------------------------------------------------------
// repack: features [32][HW] -> quad layout [8][HW] of float4.
// ---------------------------------------------------------------------------
__device__ __forceinline__ void repack_body(
    int tid, const float* __restrict__ srcf, const float* __restrict__ reff,
    float4* __restrict__ qsrc, float4* __restrict__ qref, int v, int b)
{
    int p = tid & (HW - 1);
    int g = tid >> 14;
    const float* sb = srcf + ((size_t)(v*Bn + b)) * Cn * HW + (size_t)(g*4) * HW + p;
    const float* rb = reff + ((size_t)(v*Bn + b)) * Cn * HW + (size_t)(g*4) * HW + p;
    float4 s4; s4.x = sb[0]; s4.y = sb[HW]; s4.z = sb[2*HW]; s4.w = sb[3*HW];
    float4 r4; r4.x = rb[0]; r4.y = rb[HW]; r4.z = rb[2*HW]; r4.w = rb[3*HW];
    qsrc[(size_t)g * HW + p] = s4;
    qref[(size_t)g * HW + p] = r4;
}

__global__ __launch_bounds__(256) void mega_repack(
    const float* __restrict__ srcf, const float* __restrict__ reff,
    float4* __restrict__ qs_all, float4* __restrict__ qr_all)
{
    int s = blockIdx.x >> 9;                  // / RBLK(512)
    int tid = (blockIdx.x & 511) * 256 + threadIdx.x;
    int v = s & 3, b = s >> 2;
    repack_body(tid, srcf, reff, qs_all + (size_t)s * Gn * HW,
                qr_all + (size_t)s * Gn * HW, v, b);
}

// ---------------------------------------------------------------------------
// per-bin gather+correlate (batch-16 x 2 halves, R14-proven best shape).
// f64 projection accumulation; f32 division/floor/weights.
// ---------------------------------------------------------------------------
__device__ __forceinline__ void warp_gather(
    int d, int p, double bx, double by, double bz,
    const float4* __restrict__ qsrc, const float4 rr[Gn],
    const float* __restrict__ dhT, const double* __restrict__ pr,
    int b, float cor[Gn])
{
    double depth = (double)dhT[(size_t)b * DHW + (size_t)p * Dn + d];  // coalesced
    float px = (float)(bx * depth + pr[9]);
    float py = (float)(by * depth + pr[10]);
    float pz = (float)(bz * depth + pr[11]);
    if (pz == 0.f) pz = 1e-9f;
    float invz = __frcp_rn(pz);           // xs = px/pz exactly (normalize cancels)
    float xs = px * invz;
    float ys = py * invz;
    float x0f = floorf(xs), y0f = floorf(ys);
    float wx = xs - x0f, wy = ys - y0f;
    int ix = (int)x0f, iy = (int)y0f;
    bool vx0 = (ix >= 0) && (ix < Wn), vx1 = (ix + 1 >= 0) && (ix + 1 < Wn);
    bool vy0 = (iy >= 0) && (iy < Hn), vy1 = (iy + 1 >= 0) && (iy + 1 < Hn);
    int cx0 = min(max(ix, 0), Wn-1), cx1 = min(max(ix+1, 0), Wn-1);
    int cy0 = min(max(iy, 0), Hn-1), cy1 = min(max(iy+1, 0), Hn-1);
    float a00 = (vx0 && vy0) ? (1.f-wx)*(1.f-wy) : 0.f;
    float a01 = (vx1 && vy0) ? wx*(1.f-wy)       : 0.f;
    float a10 = (vx0 && vy1) ? (1.f-wx)*wy       : 0.f;
    float a11 = (vx1 && vy1) ? wx*wy             : 0.f;
    int o00 = cy0*Wn + cx0, o01 = cy0*Wn + cx1, o10 = cy1*Wn + cx0, o11 = cy1*Wn + cx1;
    #pragma unroll
    for (int half = 0; half < 2; half++) {
        float4 T00[4], T01[4], T10[4], T11[4];
        #pragma unroll
        for (int j2 = 0; j2 < 4; j2++) {
            const float4* qs = qsrc + (size_t)(half*4 + j2) * HW;
            T00[j2] = qs[o00]; T01[j2] = qs[o01];
            T10[j2] = qs[o10]; T11[j2] = qs[o11];
        }
        #pragma unroll
        for (int j2 = 0; j2 < 4; j2++) {
            int j = half*4 + j2;
            float vx = a00*T00[j2].x + a01*T01[j2].x + a10*T10[j2].x + a11*T11[j2].x;
            float vy = a00*T00[j2].y + a01*T01[j2].y + a10*T10[j2].y + a11*T11[j2].y;
            float vz = a00*T00[j2].z + a01*T01[j2].z + a10*T10[j2].z + a11*T11[j2].z;
            float vw = a00*T00[j2].w + a01*T01[j2].w + a10*T10[j2].w + a11*T11[j2].w;
            cor[j] = ((vx*rr[j].x + vy*rr[j].y) + vz*rr[j].z) + vw*rr[j].w;
        }
    }
}

// 2-bins-per-thread quad warp: both bins computed, adjacent full-line stores.
__device__ __forceinline__ void warp_body_q2(
    int tid, const float4* __restrict__ qsrc, const float4* __restrict__ qref,
    const float* __restrict__ dhT, const double* __restrict__ projws,
    const float* sU1, const float* sU2, const float* sR,
    float2* __restrict__ ownbuf, float2* __restrict__ tapbuf, int v, int b)
{
    int dlo = tid & 15, p = tid >> 4;
    int w = p & 127, h = p >> 7;
    const double* pr = projws + (v * Bn + b) * 12;
    double xf = (double)w, yf = (double)h;
    double bx = pr[0]*xf + pr[1]*yf + pr[2];
    double by = pr[3]*xf + pr[4]*yf + pr[5];
    double bz = pr[6]*xf + pr[7]*yf + pr[8];
    float4 rr[Gn];
    #pragma unroll
    for (int j = 0; j < Gn; j++) rr[j] = qref[(size_t)j * HW + p];
    float cor0[Gn], cor1[Gn];
    warp_gather(dlo,      p, bx, by, bz, qsrc, rr, dhT, pr, b, cor0);
    warp_gather(dlo + 16, p, bx, by, bz, qsrc, rr, dhT, pr, b, cor1);
    float s0 = 0.f, r0 = 0.f, s1 = 0.f, r1 = 0.f;
    #pragma unroll
    for (int g = 0; g < Gn; g++) {
        s0 += cor0[g]; r0 += sR[g] * cor0[g];
        s1 += cor1[g]; r1 += sR[g] * cor1[g];
    }
    float2 o0; o0.x = 0.25f * s0; o0.y = 0.25f * r0;
    float2 o1; o1.x = 0.25f * s1; o1.y = 0.25f * r1;
    ownbuf[(size_t)p * Dn + dlo]      = o0;
    ownbuf[(size_t)p * Dn + dlo + 16] = o1;
    #pragma unroll
    for (int n = 0; n < Nn; n++) {
        float t10 = 0.f, t20 = 0.f, t11_ = 0.f, t21 = 0.f;
        #pragma unroll
        for (int g = 0; g < Gn; g++) {
            float u1 = sU1[g*Nn + n], u2 = sU2[g*Nn + n];
            t10 += u1 * cor0[g]; t20 += u2 * cor0[g];
            t11_ += u1 * cor1[g]; t21 += u2 * cor1[g];
        }
        float2 t0; t0.x = 0.25f * t10; t0.y = 0.25f * t20;
        float2 t1; t1.x = 0.25f * t11_; t1.y = 0.25f * t21;
        tapbuf[((size_t)p * Nn + n) * Dn + dlo]      = t0;
        tapbuf[((size_t)p * Nn + n) * Dn + dlo + 16] = t1;
    }
}

__global__ __launch_bounds__(256) void mega_warp(
    const float4* __restrict__ qs_all, const float4* __restrict__ qr_all,
    const float* __restrict__ dhT, const double* __restrict__ projws,
    const double* __restrict__ wtab,
    float2* __restrict__ own_all, float2* __restrict__ tap_all)
{
    __shared__ float sU1[Gn * Nn], sU2[Gn * Nn], sR[Gn];
    int lt = threadIdx.x;
    if (lt < Gn * Nn) { sU1[lt] = (float)wtab[8 + lt]; sU2[lt] = (float)wtab[40 + lt]; }
    if (lt < Gn) sR[lt] = (float)wtab[lt];
    __syncthreads();
    int s = blockIdx.x >> 10;                 // / WBLK(1024)
    int tid = (blockIdx.x & 1023) * 256 + lt; // covers DHW/2 (p, dlo) units
    int v = s & 3, b = s >> 2;
    warp_body_q2(tid, qs_all + (size_t)s * Gn * HW, qr_all + (size_t)s * Gn * HW,
                 dhT, projws, sU1, sU2, sR,
                 own_all + (size_t)s * DHW, tap_all + (size_t)s * Nn * DHW, v, b);
}

// ---------------------------------------------------------------------------
// warp body (scalar fallback, channel-major raw features, 1 bin/thread, f64)
// ---------------------------------------------------------------------------
__device__ __forceinline__ void warp_body(
    int tid, const float* __restrict__ srcf, const float* __restrict__ reff,
    const float* __restrict__ dh, const double* __restrict__ projws,
    const float* sU1, const float* sU2, const float* sR,
    float2* __restrict__ ownbuf, float2* __restrict__ tapbuf, int v, int b)
{
    int d = tid & 31, p = tid >> 5;
    int w = p & 127, h = p >> 7;
    const double* pr = projws + (v * Bn + b) * 12;
    double depth = (double)dh[(size_t)(b * Dn + d) * HW + p];
    double xf = (double)w, yf = (double)h;
    double px = (pr[0]*xf + pr[1]*yf + pr[2]) * depth + pr[9];
    double py = (pr[3]*xf + pr[4]*yf + pr[5]) * depth + pr[10];
    double pz = (pr[6]*xf + pr[7]*yf + pr[8]) * depth + pr[11];
    if (pz == 0.0) pz = 1e-9;
    double invz = 1.0 / pz;
    double xs = px * invz;
    double ys = py * invz;
    double x0f = floor(xs), y0f = floor(ys);
    double wx = xs - x0f, wy = ys - y0f;
    int ix = (int)x0f, iy = (int)y0f;
    bool vx0 = (ix >= 0) && (ix < Wn), vx1 = (ix + 1 >= 0) && (ix + 1 < Wn);
    bool vy0 = (iy >= 0) && (iy < Hn), vy1 = (iy + 1 >= 0) && (iy + 1 < Hn);
    int cx0 = min(max(ix, 0), Wn-1), cx1 = min(max(ix+1, 0), Wn-1);
    int cy0 = min(max(iy, 0), Hn-1), cy1 = min(max(iy+1, 0), Hn-1);
    float a00 = (vx0 && vy0) ? (float)((1.0-wx)*(1.0-wy)) : 0.f;
    float a01 = (vx1 && vy0) ? (float)(wx*(1.0-wy))       : 0.f;
    float a10 = (vx0 && vy1) ? (float)((1.0-wx)*wy)       : 0.f;
    float a11 = (vx1 && vy1) ? (float)(wx*wy)             : 0.f;
    int o00 = cy0*Wn + cx0, o01 = cy0*Wn + cx1, o10 = cy1*Wn + cx0, o11 = cy1*Wn + cx1;
    const float* sb = srcf + ((size_t)(v*Bn + b)) * Cn * HW;
    const float* rb = reff + ((size_t)(v*Bn + b)) * Cn * HW + p;
    float cor[Gn];
    #pragma unroll
    for (int g = 0; g < Gn; g++) cor[g] = 0.f;
    #pragma unroll
    for (int c = 0; c < Cn; c++) {
        const float* sc = sb + c * HW;
        float val = a00*sc[o00] + a01*sc[o01] + a10*sc[o10] + a11*sc[o11];
        cor[c >> 2] += val * rb[c * HW];
    }
    float s_own = 0.f, r_own = 0.f;
    #pragma unroll
    for (int g = 0; g < Gn; g++) { s_own += cor[g]; r_own += sR[g] * cor[g]; }
    float2 o2; o2.x = 0.25f * s_own; o2.y = 0.25f * r_own;
    ownbuf[tid] = o2;
    #pragma unroll
    for (int n = 0; n < Nn; n++) {
        float t1 = 0.f, t2 = 0.f;
        #pragma unroll
        for (int g = 0; g < Gn; g++) {
            t1 += sU1[g*Nn + n] * cor[g];
            t2 += sU2[g*Nn + n] * cor[g];
        }
        float2 t; t.x = 0.25f * t1; t.y = 0.25f * t2;
        tapbuf[((size_t)p * Nn + n) * Dn + d] = t;
    }
}

// ---------------------------------------------------------------------------
// per-view sample core, phase-batched; bilinear weights in f32 (noise ~1e-5
// on logits, 250x below tie-guard eps/2); accumulation of s,r stays f64.
// ---------------------------------------------------------------------------
__device__ __forceinline__ void sample_view(
    int d, int p, int w, int h,
    const float2* __restrict__ ownbuf, const float2* __restrict__ tapbuf,
    const float* __restrict__ grids, float* __restrict__ out_corw,
    int v, int b, double& cw_out, double& r_out)
{
    float2 ow = ownbuf[(size_t)p * Dn + d];
    const float2* gb2 = (const float2*)(grids + ((size_t)(v*Bn + b)) * Nn * HW * 2);
    float A00[Nn], A01[Nn], A10[Nn], A11[Nn];
    int O00[Nn], O01[Nn], O10[Nn], O11[Nn];
    #pragma unroll
    for (int n = 0; n < Nn; n++) {
        float2 g2 = gb2[((size_t)n * Hn + h) * Wn + w];
        float xs = (g2.x + 1.0f) * 63.5f;
        float ys = (g2.y + 1.0f) * 63.5f;
        float x0f = floorf(xs), y0f = floorf(ys);
        float wx = xs - x0f, wy = ys - y0f;
        int ix = (int)x0f, iy = (int)y0f;
        bool vx0 = (ix >= 0) && (ix < Wn), vx1 = (ix + 1 >= 0) && (ix + 1 < Wn);
        bool vy0 = (iy >= 0) && (iy < Hn), vy1 = (iy + 1 >= 0) && (iy + 1 < Hn);
        int cx0 = min(max(ix, 0), Wn-1), cx1 = min(max(ix+1, 0), Wn-1);
        int cy0 = min(max(iy, 0), Hn-1), cy1 = min(max(iy+1, 0), Hn-1);
        A00[n] = (vx0 && vy0) ? (1.f-wx)*(1.f-wy) : 0.f;
        A01[n] = (vx1 && vy0) ? wx*(1.f-wy)       : 0.f;
        A10[n] = (vx0 && vy1) ? (1.f-wx)*wy       : 0.f;
        A11[n] = (vx1 && vy1) ? wx*wy             : 0.f;
        O00[n] = cy0*Wn + cx0; O01[n] = cy0*Wn + cx1;
        O10[n] = cy1*Wn + cx0; O11[n] = cy1*Wn + cx1;
    }
    float2 Q00[Nn], Q01[Nn], Q10[Nn], Q11[Nn];
    #pragma unroll
    for (int n = 0; n < Nn; n++) {
        Q00[n] = tapbuf[((size_t)O00[n] * Nn + n) * Dn + d];
        Q01[n] = tapbuf[((size_t)O01[n] * Nn + n) * Dn + d];
        Q10[n] = tapbuf[((size_t)O10[n] * Nn + n) * Dn + d];
        Q11[n] = tapbuf[((size_t)O11[n] * Nn + n) * Dn + d];
    }
    double s = (double)ow.x, r = (double)ow.y;
    #pragma unroll
    for (int n = 0; n < Nn; n++) {
        // f32 weight*tap products, accumulated in f64 (per-n order preserved)
        float sx = A00[n]*Q00[n].x + A01[n]*Q01[n].x
                 + A10[n]*Q10[n].x + A11[n]*Q11[n].x;
        float rx = A00[n]*Q00[n].y + A01[n]*Q01[n].y
                 + A10[n]*Q10[n].y + A11[n]*Q11[n].y;
        s += (double)sx;
        r += (double)rx;
    }
    double logit = s * 0.5;                       // / ATTN_TEMP
    double m = logit;
    #pragma unroll
    for (int mask = 16; mask >= 1; mask >>= 1) m = fmax(m, __shfl_xor(m, mask));
    double e = exp(logit - m);
    double ssum = e;
    #pragma unroll
    for (int mask = 16; mask >= 1; mask >>= 1) ssum += __shfl_xor(ssum, mask);
    const double SQRTC = 5.656854249492381;       // sqrt(32)
    if (d == 0) out_corw[(size_t)v * BHW + (size_t)b * HW + p] = (float)(1.0 / ssum / SQRTC);
    cw_out = e / ssum / SQRTC;
    r_out = r;
}

// ---------------------------------------------------------------------------
// finalize core: attn softmax + top-2 tie-guard argmax (eps = 5e-3, proven).
// ---------------------------------------------------------------------------
__device__ __forceinline__ void finalize_core(
    int d, int p, int b, double cs, double wr,
    const float* __restrict__ depth_hypo, float* __restrict__ out)
{
    double lg = wr / cs;
    double fm = lg;
    #pragma unroll
    for (int mask = 16; mask >= 1; mask >>= 1) fm = fmax(fm, __shfl_xor(fm, mask));
    double fe = exp(lg - fm);
    double fsum = fe;
    #pragma unroll
    for (int mask = 16; mask >= 1; mask >>= 1) fsum += __shfl_xor(fsum, mask);
    out[2*BHW + (size_t)b * DHW + (size_t)d * HW + p] = (float)(fe / fsum); // attn_weight
    double bv = lg; int bi = d;
    #pragma unroll
    for (int mask = 16; mask >= 1; mask >>= 1) {
        double ov = __shfl_xor(bv, mask);
        int oi = __shfl_xor(bi, mask);
        if (ov > bv || (ov == bv && oi < bi)) { bv = ov; bi = oi; }
    }
    double rv = (d == bi) ? -1e300 : lg; int ri = d;
    #pragma unroll
    for (int mask = 16; mask >= 1; mask >>= 1) {
        double ov = __shfl_xor(rv, mask);
        int oi = __shfl_xor(ri, mask);
        if (ov > rv || (ov == rv && oi < ri)) { rv = ov; ri = oi; }
    }
    if (d == 0) {
        const float* dhb = depth_hypo + (size_t)b * DHW + p;   // + j*HW
        double eps = 5e-3 * (1.0 + fabs(bv));
        bool adj = (ri == bi + 1) || (ri == bi - 1);
        float dep;
        if (adj && (bv - rv) <= eps)
            dep = 0.5f * (dhb[(size_t)bi * HW] + dhb[(size_t)ri * HW]);  // tie midpoint
        else
            dep = dhb[(size_t)bi * HW];
        out[(size_t)b * HW + p] = dep;                                   // depth
        out[BHW + (size_t)b * HW + p] = (float)(1.0 / fsum);             // confidence
    }
}

// ---------------------------------------------------------------------------
// mega_sample: loops v in registers, finalizes inline.
// ---------------------------------------------------------------------------
__global__ __launch_bounds__(256, 3) void mega_sample(
    const float2* __restrict__ own_all, const float2* __restrict__ tap_all,
    const float* __restrict__ grids, const float* __restrict__ dh,
    float* __restrict__ out_corw, float* __restrict__ out)
{
    int tid = blockIdx.x * 256 + threadIdx.x;  // over BDHW
    int d = tid & 31;
    int p = (tid >> 5) & (HW - 1);
    int b = tid >> 19;
    int w = p & 127, h = p >> 7;
    double cs = 1e-8, wr = 0.0;
    for (int v = 0; v < Vv; v++) {
        int s = b * 4 + v;
        double cw, r;
        sample_view(d, p, w, h, own_all + (size_t)s * DHW,
                    tap_all + (size_t)s * Nn * DHW, grids, out_corw, v, b, cw, r);
        cs += cw;
        wr += cw * r;
    }
    finalize_core(d, p, b, cs, wr, dh, out);
}

// ---------------------------------------------------------------------------
// fallback kernels (serial / pipe structures, 1-bin scalar warp)
// ---------------------------------------------------------------------------
template <int MODE>
__device__ __forceinline__ void sample_body(
    int tid, const float2* __restrict__ ownbuf, const float2* __restrict__ tapbuf,
    const float* __restrict__ grids, float2* __restrict__ accf,
    float* __restrict__ out_corw, const float* __restrict__ depth_hypo,
    float* __restrict__ out, int v, int b)
{
    int d = tid & 31;
    int p = tid >> 5;
    int w = p & 127, h = p >> 7;
    double cw, r;
    sample_view(d, p, w, h, ownbuf, tapbuf, grids, out_corw, v, b, cw, r);
    if (MODE == 0) {
        float2 a; a.x = (float)(1e-8 + cw); a.y = (float)(cw * r);
        accf[tid] = a;
    } else if (MODE == 1) {
        float2 a = accf[tid];
        a.x = (float)((double)a.x + cw);
        a.y = (float)((double)a.y + cw * r);
        accf[tid] = a;
    } else {
        float2 a = accf[tid];
        finalize_core(d, p, b, (double)a.x + cw, (double)a.y + cw * r, depth_hypo, out);
    }
}

__global__ __launch_bounds__(256) void warp_corr(
    const float* __restrict__ srcf, const float* __restrict__ reff,
    const float* __restrict__ dh, const double* __restrict__ projws,
    const double* __restrict__ wtab,
    float2* __restrict__ ownbuf, float2* __restrict__ tapbuf, int v, int b)
{
    __shared__ float sU1[Gn * Nn], sU2[Gn * Nn], sR[Gn];
    int lt = threadIdx.x;
    if (lt < Gn * Nn) { sU1[lt] = (float)wtab[8 + lt]; sU2[lt] = (float)wtab[40 + lt]; }
    if (lt < Gn) sR[lt] = (float)wtab[lt];
    __syncthreads();
    warp_body(blockIdx.x * 256 + lt, srcf, reff, dh, projws, sU1, sU2, sR,
              ownbuf, tapbuf, v, b);
}

template <int MODE>
__global__ __launch_bounds__(256) void sample_enh(
    const float2* __restrict__ ownbuf, const float2* __restrict__ tapbuf,
    const float* __restrict__ grids, float2* __restrict__ accf,
    float* __restrict__ out_corw, const float* __restrict__ depth_hypo,
    float* __restrict__ out, int v, int b)
{
    sample_body<MODE>(blockIdx.x * 256 + threadIdx.x, ownbuf, tapbuf, grids,
                      accf, out_corw, depth_hypo, out, v, b);
}

template <int MODE>
__global__ __launch_bounds__(256) void fused_sw(
    const float* __restrict__ srcf, const float* __restrict__ reff,
    const float* __restrict__ dh, const double* __restrict__ projws,
    const double* __restrict__ wtab, const float* __restrict__ grids,
    const float2* __restrict__ ownR, const float2* __restrict__ tapR,
    float2* __restrict__ ownW, float2* __restrict__ tapW,
    float2* __restrict__ accf, float* __restrict__ out_corw,
    float* __restrict__ out, int vs, int bs, int vw, int bw)
{
    int lt = threadIdx.x;
    int role = blockIdx.x & 1;
    int vb   = blockIdx.x >> 1;
    if (role == 0) {
        sample_body<MODE>(vb * 256 + lt, ownR, tapR, grids,
                          accf, out_corw, dh, out, vs, bs);
    } else {
        __shared__ float sU1[Gn * Nn], sU2[Gn * Nn], sR[Gn];
        if (lt < Gn * Nn) { sU1[lt] = (float)wtab[8 + lt]; sU2[lt] = (float)wtab[40 + lt]; }
        if (lt < Gn) sR[lt] = (float)wtab[lt];
        __syncthreads();
        warp_body(vb * 256 + lt, srcf, reff, dh, projws,
                  sU1, sU2, sR, ownW, tapW, vw, bw);
    }
}

// ---------------------------------------------------------------------------
extern "C" void kernel_launch(void* const* d_in, const int* in_sizes, int n_in,
                              void* d_out, int out_size, void* d_ws, size_t ws_size,
                              hipStream_t stream) {
    const float* reff  = (const float*)d_in[0];  // (V,B,C,H,W)
    const float* srcf  = (const float*)d_in[1];  // (V,B,C,H,W)
    const float* pm    = (const float*)d_in[2];  // (B,V+1,2,4,4)
    const float* dh    = (const float*)d_in[3];  // (B,D,H,W)
    const float* grids = (const float*)d_in[4];  // (V,B,N,H,W,2)
    const float* wreg  = (const float*)d_in[5];  // (G,)
    const float* wenh  = (const float*)d_in[6];  // (G,G*N)
    float* out = (float*)d_out;
    double* projws = (double*)d_ws;
    double* wtab   = (double*)((char*)d_ws + 1024);
    char*   base   = (char*)d_ws + 2048;
    // mega layout: tap_all [8][4*DHW] f2 (134.2MB) | own_all [8][DHW] f2 (33.6MB)
    //   | qs_all [8][Gn*HW] f4 (16.8MB) | qr_all (16.8MB) | dhT f32 BDHW (4.2MB)
    float2* tap_all = (float2*)base;
    float2* own_all = tap_all + (size_t)NST * Nn * DHW;
    float4* qs_all  = (float4*)(own_all + (size_t)NST * DHW);
    float4* qr_all  = qs_all + (size_t)NST * Gn * HW;
    float*  dhT     = (float*)(qr_all + (size_t)NST * Gn * HW);
    size_t need_mega = 2048 + (size_t)NST * Nn * DHW * 8 + (size_t)NST * DHW * 8
                     + 2 * (size_t)NST * Gn * HW * 16 + (size_t)BDHW * 4;
    // fallback layout (overlays same region):
    float2* accf = (float2*)base;
    float2* own0 = accf + DHW;
    float2* tap0 = own0 + DHW;
    float2* own1 = tap0 + (size_t)DHW * Nn;
    float2* tap1 = own1 + DHW;
    size_t need_pipe = 2048 + (size_t)DHW * 8 + 2 * ((size_t)DHW * 8 + (size_t)DHW * Nn * 8);

    setup_proj<<<1, 64, 0, stream>>>(pm, wenh, wreg, projws, wtab);
    float* out_corw = out + 2*BHW + BDHW;

    if (ws_size >= need_mega) {
        transpose_depth<<<dim3(HW/32, Bn), dim3(32, 8), 0, stream>>>(dh, dhT);
        mega_repack<<<NST * RBLK, 256, 0, stream>>>(srcf, reff, qs_all, qr_all);
        mega_warp<<<NST * WBLK, 256, 0, stream>>>(qs_all, qr_all, dhT, projws,
                                                  wtab, own_all, tap_all);
        mega_sample<<<SBLK, 256, 0, stream>>>(own_all, tap_all, grids, dh,
                                              out_corw, out);
    } else if (ws_size >= need_pipe) {
        float2* owns[2] = { own0, own1 };
        float2* taps[2] = { tap0, tap1 };
        warp_corr<<<NBLK, 256, 0, stream>>>(srcf, reff, dh, projws, wtab,
                                            own0, tap0, 0, 0);
        for (int k = 1; k < 8; k++) {
            int vs = (k - 1) & 3, bs = (k - 1) >> 2;
            int vw = k & 3,       bw = k >> 2;
            float2* oR = owns[(k - 1) & 1]; float2* tR = taps[(k - 1) & 1];
            float2* oW = owns[k & 1];       float2* tW = taps[k & 1];
            if (vs == 0)
                fused_sw<0><<<2*NBLK, 256, 0, stream>>>(srcf, reff, dh, projws, wtab, grids,
                                                        oR, tR, oW, tW, accf,
                                                        out_corw, out, vs, bs, vw, bw);
            else if (vs == 3)
                fused_sw<2><<<2*NBLK, 256, 0, stream>>>(srcf, reff, dh, projws, wtab, grids,
                                                        oR, tR, oW, tW, accf,
                                                        out_corw, out, vs, bs, vw, bw);
            else
                fused_sw<1><<<2*NBLK, 256, 0, stream>>>(srcf, reff, dh, projws, wtab, grids,
                                                        oR, tR, oW, tW, accf,
                                                        out_corw, out, vs, bs, vw, bw);
        }
        sample_enh<2><<<NBLK, 256, 0, stream>>>(owns[1], taps[1], grids, accf,
                                                out_corw, dh, out, 3, 1);
    } else {
        for (int b = 0; b < Bn; b++) {
            for (int v = 0; v < Vv; v++) {
                warp_corr<<<NBLK, 256, 0, stream>>>(srcf, reff, dh, projws, wtab,
                                                    own0, tap0, v, b);
                if (v == 0)
                    sample_enh<0><<<NBLK, 256, 0, stream>>>(own0, tap0, grids, accf,
                                                            out_corw, dh, out, v, b);
                else if (v < Vv - 1)
                    sample_enh<1><<<NBLK, 256, 0, stream>>>(own0, tap0, grids, accf,
                                                            out_corw, dh, out, v, b);
                else
                    sample_enh<2><<<NBLK, 256, 0, stream>>>(own0, tap0, grids, accf,
                                                            out_corw, dh, out, v, b);
            }
        }
    }
}

// Round 21
// 184.738 us; speedup vs baseline: 1.0428x; 1.0428x over previous
//
#include <hip/hip_runtime.h>

// Problem constants (match reference)
#define Vv 4
#define Bn 2
#define Cn 32
#define Hn 128
#define Wn 128
#define Dn 32
#define Gn 8
#define Nn 4
// derived
#define HW (Hn*Wn)            // 16384
#define BHW (Bn*Hn*Wn)        // 32768
#define DHW (Dn*Hn*Wn)        // 524288
#define BDHW (Bn*Dn*Hn*Wn)    // 1048576
#define NBLK (DHW/256)        // 2048 blocks per warp stage (1-bin mapping)
#define WBLK (DHW/512)        // 1024 blocks per warp stage (2-bin mapping)
#define RBLK (Gn*HW/256)      // 512 repack blocks per stage
#define NST  (Vv*Bn)          // 8 stages

// ---------------------------------------------------------------------------
// setup: per (v,b) P = src_proj_new @ inv(ref_proj_new) in f64, plus
// wtab[0..7]=w_reg, wtab[8+k]=u1[k], wtab[40+k]=u2[k]
// ---------------------------------------------------------------------------
__global__ void setup_proj(const float* __restrict__ pm,
                           const float* __restrict__ wenh,
                           const float* __restrict__ wreg,
                           double* __restrict__ projws,
                           double* __restrict__ wtab) {
    int t = threadIdx.x;
    if (t < Gn) wtab[t] = (double)wreg[t];
    if (t < Gn * Nn) {
        double a = 0.0, c = 0.0;
        for (int g = 0; g < Gn; g++) {
            double wv = (double)wenh[g * (Gn * Nn) + t];
            a += wv;
            c += (double)wreg[g] * wv;
        }
        wtab[8 + t] = a; wtab[40 + t] = c;
    }
    if (t >= Vv * Bn) return;
    int v = t / Bn, b = t % Bn;
    const float* Eref = pm + (((size_t)b * (Vv + 1) + 0) * 2 + 0) * 16;
    const float* Kref = pm + (((size_t)b * (Vv + 1) + 0) * 2 + 1) * 16;
    const float* Esrc = pm + (((size_t)b * (Vv + 1) + (v + 1)) * 2 + 0) * 16;
    const float* Ksrc = pm + (((size_t)b * (Vv + 1) + (v + 1)) * 2 + 1) * 16;
    double R[16], S[16];
    for (int r = 0; r < 3; r++)
        for (int c = 0; c < 4; c++) {
            R[r*4+c] = (double)Kref[r*4+0]*Eref[0*4+c] + (double)Kref[r*4+1]*Eref[1*4+c] + (double)Kref[r*4+2]*Eref[2*4+c];
            S[r*4+c] = (double)Ksrc[r*4+0]*Esrc[0*4+c] + (double)Ksrc[r*4+1]*Esrc[1*4+c] + (double)Ksrc[r*4+2]*Esrc[2*4+c];
        }
    for (int c = 0; c < 4; c++) { R[12+c] = Eref[12+c]; S[12+c] = Esrc[12+c]; }
    double M[4][8];
    for (int r = 0; r < 4; r++)
        for (int c = 0; c < 4; c++) { M[r][c] = R[r*4+c]; M[r][4+c] = (r == c) ? 1.0 : 0.0; }
    for (int col = 0; col < 4; col++) {
        int piv = col; double best = fabs(M[col][col]);
        for (int r = col+1; r < 4; r++) { double a = fabs(M[r][col]); if (a > best) { best = a; piv = r; } }
        if (piv != col)
            for (int c = 0; c < 8; c++) { double tmp = M[col][c]; M[col][c] = M[piv][c]; M[piv][c] = tmp; }
        double inv = 1.0 / M[col][col];
        for (int c = 0; c < 8; c++) M[col][c] *= inv;
        for (int r = 0; r < 4; r++) if (r != col) {
            double f = M[r][col];
            for (int c = 0; c < 8; c++) M[r][c] -= f * M[col][c];
        }
    }
    double P[16];
    for (int r = 0; r < 4; r++)
        for (int c = 0; c < 4; c++) {
            double acc = 0.0;
            for (int k = 0; k < 4; k++) acc += S[r*4+k] * M[k][4+c];
            P[r*4+c] = acc;
        }
    double* o = projws + t * 12;
    o[0]=P[0];  o[1]=P[1];  o[2]=P[2];
    o[3]=P[4];  o[4]=P[5];  o[5]=P[6];
    o[6]=P[8];  o[7]=P[9];  o[8]=P[10];
    o[9]=P[3];  o[10]=P[7]; o[11]=P[11];
}

// ---------------------------------------------------------------------------
// repack: features [32][HW] -> quad layout [8][HW] of float4.
// ---------------------------------------------------------------------------
__device__ __forceinline__ void repack_body(
    int tid, const float* __restrict__ srcf, const float* __restrict__ reff,
    float4* __restrict__ qsrc, float4* __restrict__ qref, int v, int b)
{
    int p = tid & (HW - 1);
    int g = tid >> 14;
    const float* sb = srcf + ((size_t)(v*Bn + b)) * Cn * HW + (size_t)(g*4) * HW + p;
    const float* rb = reff + ((size_t)(v*Bn + b)) * Cn * HW + (size_t)(g*4) * HW + p;
    float4 s4; s4.x = sb[0]; s4.y = sb[HW]; s4.z = sb[2*HW]; s4.w = sb[3*HW];
    float4 r4; r4.x = rb[0]; r4.y = rb[HW]; r4.z = rb[2*HW]; r4.w = rb[3*HW];
    qsrc[(size_t)g * HW + p] = s4;
    qref[(size_t)g * HW + p] = r4;
}

// ---------------------------------------------------------------------------
// per-bin quad warp core: homography (f64, one division) + batched f32
// bilinear/correlate -> writes own (s,r) float2 and 4 tap float2.
// ---------------------------------------------------------------------------
__device__ __forceinline__ void warp_bin_q(
    int d, int p, double bx, double by, double bz,
    const float4* __restrict__ qsrc, const float4* __restrict__ qref,
    const float* __restrict__ dh, const double* __restrict__ pr,
    const float* sU1, const float* sU2, const float* sR,
    float2* __restrict__ ownbuf, float2* __restrict__ tapbuf, int b)
{
    double depth = (double)dh[(size_t)(b * Dn + d) * HW + p];
    double px = bx * depth + pr[9];
    double py = by * depth + pr[10];
    double pz = bz * depth + pr[11];
    if (pz == 0.0) pz = 1e-9;
    double invz = 1.0 / pz;               // xs = px/pz exactly (normalize cancels)
    double xs = px * invz;
    double ys = py * invz;
    double x0f = floor(xs), y0f = floor(ys);
    double wx = xs - x0f, wy = ys - y0f;
    int ix = (int)x0f, iy = (int)y0f;
    bool vx0 = (ix >= 0) && (ix < Wn), vx1 = (ix + 1 >= 0) && (ix + 1 < Wn);
    bool vy0 = (iy >= 0) && (iy < Hn), vy1 = (iy + 1 >= 0) && (iy + 1 < Hn);
    int cx0 = min(max(ix, 0), Wn-1), cx1 = min(max(ix+1, 0), Wn-1);
    int cy0 = min(max(iy, 0), Hn-1), cy1 = min(max(iy+1, 0), Hn-1);
    float a00 = (vx0 && vy0) ? (float)((1.0-wx)*(1.0-wy)) : 0.f;
    float a01 = (vx1 && vy0) ? (float)(wx*(1.0-wy))       : 0.f;
    float a10 = (vx0 && vy1) ? (float)((1.0-wx)*wy)       : 0.f;
    float a11 = (vx1 && vy1) ? (float)(wx*wy)             : 0.f;
    int o00 = cy0*Wn + cx0, o01 = cy0*Wn + cx1, o10 = cy1*Wn + cx0, o11 = cy1*Wn + cx1;
    float cor[Gn];
    // two batches of 4 groups; 16 loads issued per batch before consumption
    #pragma unroll
    for (int half = 0; half < 2; half++) {
        float4 T00[4], T01[4], T10[4], T11[4];
        #pragma unroll
        for (int j2 = 0; j2 < 4; j2++) {
            const float4* qs = qsrc + (size_t)(half*4 + j2) * HW;
            T00[j2] = qs[o00]; T01[j2] = qs[o01];
            T10[j2] = qs[o10]; T11[j2] = qs[o11];
        }
        #pragma unroll
        for (int j2 = 0; j2 < 4; j2++) {
            int j = half*4 + j2;
            float4 rr = qref[(size_t)j * HW + p];
            float vx = a00*T00[j2].x + a01*T01[j2].x + a10*T10[j2].x + a11*T11[j2].x;
            float vy = a00*T00[j2].y + a01*T01[j2].y + a10*T10[j2].y + a11*T11[j2].y;
            float vz = a00*T00[j2].z + a01*T01[j2].z + a10*T10[j2].z + a11*T11[j2].z;
            float vw = a00*T00[j2].w + a01*T01[j2].w + a10*T10[j2].w + a11*T11[j2].w;
            cor[j] = ((vx*rr.x + vy*rr.y) + vz*rr.z) + vw*rr.w;
        }
    }
    float s_own = 0.f, r_own = 0.f;
    #pragma unroll
    for (int g = 0; g < Gn; g++) { s_own += cor[g]; r_own += sR[g] * cor[g]; }
    float2 o2; o2.x = 0.25f * s_own; o2.y = 0.25f * r_own;
    ownbuf[(size_t)p * Dn + d] = o2;
    #pragma unroll
    for (int n = 0; n < Nn; n++) {
        float t1 = 0.f, t2 = 0.f;
        #pragma unroll
        for (int g = 0; g < Gn; g++) {
            t1 += sU1[g*Nn + n] * cor[g];
            t2 += sU2[g*Nn + n] * cor[g];
        }
        float2 t; t.x = 0.25f * t1; t.y = 0.25f * t2;
        tapbuf[((size_t)p * Nn + n) * Dn + d] = t;
    }
}

// 2-bins-per-thread wrapper: tid covers (p, dlo) with dlo in [0,16)
__device__ __forceinline__ void warp_body_q2(
    int tid, const float4* __restrict__ qsrc, const float4* __restrict__ qref,
    const float* __restrict__ dh, const double* __restrict__ projws,
    const float* sU1, const float* sU2, const float* sR,
    float2* __restrict__ ownbuf, float2* __restrict__ tapbuf, int v, int b)
{
    int dlo = tid & 15, p = tid >> 4;
    int w = p & 127, h = p >> 7;
    const double* pr = projws + (v * Bn + b) * 12;
    double xf = (double)w, yf = (double)h;
    double bx = pr[0]*xf + pr[1]*yf + pr[2];
    double by = pr[3]*xf + pr[4]*yf + pr[5];
    double bz = pr[6]*xf + pr[7]*yf + pr[8];
    #pragma unroll
    for (int e = 0; e < 2; e++)
        warp_bin_q(dlo + 16*e, p, bx, by, bz, qsrc, qref, dh, pr,
                   sU1, sU2, sR, ownbuf, tapbuf, b);
}

// ---------------------------------------------------------------------------
// warp body (scalar fallback, channel-major raw features, 1 bin/thread)
// ---------------------------------------------------------------------------
__device__ __forceinline__ void warp_body(
    int tid, const float* __restrict__ srcf, const float* __restrict__ reff,
    const float* __restrict__ dh, const double* __restrict__ projws,
    const float* sU1, const float* sU2, const float* sR,
    float2* __restrict__ ownbuf, float2* __restrict__ tapbuf, int v, int b)
{
    int d = tid & 31, p = tid >> 5;
    int w = p & 127, h = p >> 7;
    const double* pr = projws + (v * Bn + b) * 12;
    double depth = (double)dh[(size_t)(b * Dn + d) * HW + p];
    double xf = (double)w, yf = (double)h;
    double px = (pr[0]*xf + pr[1]*yf + pr[2]) * depth + pr[9];
    double py = (pr[3]*xf + pr[4]*yf + pr[5]) * depth + pr[10];
    double pz = (pr[6]*xf + pr[7]*yf + pr[8]) * depth + pr[11];
    if (pz == 0.0) pz = 1e-9;
    double invz = 1.0 / pz;
    double xs = px * invz;
    double ys = py * invz;
    double x0f = floor(xs), y0f = floor(ys);
    double wx = xs - x0f, wy = ys - y0f;
    int ix = (int)x0f, iy = (int)y0f;
    bool vx0 = (ix >= 0) && (ix < Wn), vx1 = (ix + 1 >= 0) && (ix + 1 < Wn);
    bool vy0 = (iy >= 0) && (iy < Hn), vy1 = (iy + 1 >= 0) && (iy + 1 < Hn);
    int cx0 = min(max(ix, 0), Wn-1), cx1 = min(max(ix+1, 0), Wn-1);
    int cy0 = min(max(iy, 0), Hn-1), cy1 = min(max(iy+1, 0), Hn-1);
    float a00 = (vx0 && vy0) ? (float)((1.0-wx)*(1.0-wy)) : 0.f;
    float a01 = (vx1 && vy0) ? (float)(wx*(1.0-wy))       : 0.f;
    float a10 = (vx0 && vy1) ? (float)((1.0-wx)*wy)       : 0.f;
    float a11 = (vx1 && vy1) ? (float)(wx*wy)             : 0.f;
    int o00 = cy0*Wn + cx0, o01 = cy0*Wn + cx1, o10 = cy1*Wn + cx0, o11 = cy1*Wn + cx1;
    const float* sb = srcf + ((size_t)(v*Bn + b)) * Cn * HW;
    const float* rb = reff + ((size_t)(v*Bn + b)) * Cn * HW + p;
    float cor[Gn];
    #pragma unroll
    for (int g = 0; g < Gn; g++) cor[g] = 0.f;
    #pragma unroll
    for (int c = 0; c < Cn; c++) {
        const float* sc = sb + c * HW;
        float val = a00*sc[o00] + a01*sc[o01] + a10*sc[o10] + a11*sc[o11];
        cor[c >> 2] += val * rb[c * HW];
    }
    float s_own = 0.f, r_own = 0.f;
    #pragma unroll
    for (int g = 0; g < Gn; g++) { s_own += cor[g]; r_own += sR[g] * cor[g]; }
    float2 o2; o2.x = 0.25f * s_own; o2.y = 0.25f * r_own;
    ownbuf[tid] = o2;
    #pragma unroll
    for (int n = 0; n < Nn; n++) {
        float t1 = 0.f, t2 = 0.f;
        #pragma unroll
        for (int g = 0; g < Gn; g++) {
            t1 += sU1[g*Nn + n] * cor[g];
            t2 += sU2[g*Nn + n] * cor[g];
        }
        float2 t; t.x = 0.25f * t1; t.y = 0.25f * t2;
        tapbuf[((size_t)p * Nn + n) * Dn + d] = t;
    }
}

// ---------------------------------------------------------------------------
// per-view sample core: returns (cw, r) for this (v,b,p,d); writes corw.
// ---------------------------------------------------------------------------
__device__ __forceinline__ void sample_view(
    int d, int p, int w, int h,
    const float2* __restrict__ ownbuf, const float2* __restrict__ tapbuf,
    const float* __restrict__ grids, float* __restrict__ out_corw,
    int v, int b, double& cw_out, double& r_out)
{
    float2 ow = ownbuf[(size_t)p * Dn + d];
    double s = (double)ow.x, r = (double)ow.y;
    const float2* gb2 = (const float2*)(grids + ((size_t)(v*Bn + b)) * Nn * HW * 2);
    #pragma unroll
    for (int n = 0; n < Nn; n++) {
        float2 g2 = gb2[((size_t)n * Hn + h) * Wn + w];
        double gx = (double)g2.x, gy = (double)g2.y;
        double xs = (gx + 1.0) * 63.5;
        double ys = (gy + 1.0) * 63.5;
        double x0f = floor(xs), y0f = floor(ys);
        double wx = xs - x0f, wy = ys - y0f;
        int ix = (int)x0f, iy = (int)y0f;
        bool vx0 = (ix >= 0) && (ix < Wn), vx1 = (ix + 1 >= 0) && (ix + 1 < Wn);
        bool vy0 = (iy >= 0) && (iy < Hn), vy1 = (iy + 1 >= 0) && (iy + 1 < Hn);
        int cx0 = min(max(ix, 0), Wn-1), cx1 = min(max(ix+1, 0), Wn-1);
        int cy0 = min(max(iy, 0), Hn-1), cy1 = min(max(iy+1, 0), Hn-1);
        double a00 = (vx0 && vy0) ? (1.0-wx)*(1.0-wy) : 0.0;
        double a01 = (vx1 && vy0) ? wx*(1.0-wy)       : 0.0;
        double a10 = (vx0 && vy1) ? (1.0-wx)*wy       : 0.0;
        double a11 = (vx1 && vy1) ? wx*wy             : 0.0;
        float2 q00 = tapbuf[((size_t)(cy0*Wn + cx0) * Nn + n) * Dn + d];
        float2 q01 = tapbuf[((size_t)(cy0*Wn + cx1) * Nn + n) * Dn + d];
        float2 q10 = tapbuf[((size_t)(cy1*Wn + cx0) * Nn + n) * Dn + d];
        float2 q11 = tapbuf[((size_t)(cy1*Wn + cx1) * Nn + n) * Dn + d];
        s += a00*(double)q00.x + a01*(double)q01.x + a10*(double)q10.x + a11*(double)q11.x;
        r += a00*(double)q00.y + a01*(double)q01.y + a10*(double)q10.y + a11*(double)q11.y;
    }
    double logit = s * 0.5;                       // / ATTN_TEMP
    double m = logit;
    #pragma unroll
    for (int mask = 16; mask >= 1; mask >>= 1) m = fmax(m, __shfl_xor(m, mask));
    double e = exp(logit - m);
    double ssum = e;
    #pragma unroll
    for (int mask = 16; mask >= 1; mask >>= 1) ssum += __shfl_xor(ssum, mask);
    const double SQRTC = 5.656854249492381;       // sqrt(32)
    if (d == 0) out_corw[(size_t)v * BHW + (size_t)b * HW + p] = (float)(1.0 / ssum / SQRTC);
    cw_out = e / ssum / SQRTC;
    r_out = r;
}

// ---------------------------------------------------------------------------
// finalize core: attn softmax + top-2 tie-guard argmax (eps = 5e-3, proven).
// ---------------------------------------------------------------------------
__device__ __forceinline__ void finalize_core(
    int d, int p, int b, double cs, double wr,
    const float* __restrict__ depth_hypo, float* __restrict__ out)
{
    double lg = wr / cs;
    double fm = lg;
    #pragma unroll
    for (int mask = 16; mask >= 1; mask >>= 1) fm = fmax(fm, __shfl_xor(fm, mask));
    double fe = exp(lg - fm);
    double fsum = fe;
    #pragma unroll
    for (int mask = 16; mask >= 1; mask >>= 1) fsum += __shfl_xor(fsum, mask);
    out[2*BHW + (size_t)b * DHW + (size_t)d * HW + p] = (float)(fe / fsum); // attn_weight
    double bv = lg; int bi = d;
    #pragma unroll
    for (int mask = 16; mask >= 1; mask >>= 1) {
        double ov = __shfl_xor(bv, mask);
        int oi = __shfl_xor(bi, mask);
        if (ov > bv || (ov == bv && oi < bi)) { bv = ov; bi = oi; }
    }
    double rv = (d == bi) ? -1e300 : lg; int ri = d;
    #pragma unroll
    for (int mask = 16; mask >= 1; mask >>= 1) {
        double ov = __shfl_xor(rv, mask);
        int oi = __shfl_xor(ri, mask);
        if (ov > rv || (ov == rv && oi < ri)) { rv = ov; ri = oi; }
    }
    if (d == 0) {
        const float* dhb = depth_hypo + (size_t)b * DHW + p;   // + j*HW
        double eps = 5e-3 * (1.0 + fabs(bv));
        bool adj = (ri == bi + 1) || (ri == bi - 1);
        float dep;
        if (adj && (bv - rv) <= eps)
            dep = 0.5f * (dhb[(size_t)bi * HW] + dhb[(size_t)ri * HW]);  // tie midpoint
        else
            dep = dhb[(size_t)bi * HW];
        out[(size_t)b * HW + p] = dep;                                   // depth
        out[BHW + (size_t)b * HW + p] = (float)(1.0 / fsum);             // confidence
    }
}

// ---------------------------------------------------------------------------
// MEGA kernels (4-launch schedule)
// ---------------------------------------------------------------------------
__global__ __launch_bounds__(256) void mega_repack(
    const float* __restrict__ srcf, const float* __restrict__ reff,
    float4* __restrict__ qs_all, float4* __restrict__ qr_all)
{
    int s = blockIdx.x >> 9;                  // / RBLK(512)
    int tid = (blockIdx.x & 511) * 256 + threadIdx.x;
    int v = s & 3, b = s >> 2;
    repack_body(tid, srcf, reff, qs_all + (size_t)s * Gn * HW,
                qr_all + (size_t)s * Gn * HW, v, b);
}

__global__ __launch_bounds__(256) void mega_warp(
    const float4* __restrict__ qs_all, const float4* __restrict__ qr_all,
    const float* __restrict__ dh, const double* __restrict__ projws,
    const double* __restrict__ wtab,
    float2* __restrict__ own_all, float2* __restrict__ tap_all)
{
    __shared__ float sU1[Gn * Nn], sU2[Gn * Nn], sR[Gn];
    int lt = threadIdx.x;
    if (lt < Gn * Nn) { sU1[lt] = (float)wtab[8 + lt]; sU2[lt] = (float)wtab[40 + lt]; }
    if (lt < Gn) sR[lt] = (float)wtab[lt];
    __syncthreads();
    int s = blockIdx.x >> 10;                 // / WBLK(1024)
    int tid = (blockIdx.x & 1023) * 256 + lt; // covers DHW/2 (p, dlo) units
    int v = s & 3, b = s >> 2;
    warp_body_q2(tid, qs_all + (size_t)s * Gn * HW, qr_all + (size_t)s * Gn * HW,
                 dh, projws, sU1, sU2, sR,
                 own_all + (size_t)s * DHW, tap_all + (size_t)s * Nn * DHW, v, b);
}

__global__ __launch_bounds__(256) void mega_sample(
    const float2* __restrict__ own_all, const float2* __restrict__ tap_all,
    const float* __restrict__ grids, const float* __restrict__ dh,
    float* __restrict__ out_corw, float* __restrict__ out)
{
    int tid = blockIdx.x * 256 + threadIdx.x;  // over BDHW
    int d = tid & 31;
    int p = (tid >> 5) & (HW - 1);
    int b = tid >> 19;
    int w = p & 127, h = p >> 7;
    double cs = 1e-8, wr = 0.0;
    for (int v = 0; v < Vv; v++) {
        int s = b * 4 + v;
        double cw, r;
        sample_view(d, p, w, h, own_all + (size_t)s * DHW,
                    tap_all + (size_t)s * Nn * DHW, grids, out_corw, v, b, cw, r);
        cs += cw;
        wr += cw * r;
    }
    finalize_core(d, p, b, cs, wr, dh, out);
}

// ---------------------------------------------------------------------------
// fallback kernels (serial / pipe structures, 1-bin scalar warp)
// ---------------------------------------------------------------------------
template <int MODE>
__device__ __forceinline__ void sample_body(
    int tid, const float2* __restrict__ ownbuf, const float2* __restrict__ tapbuf,
    const float* __restrict__ grids, float2* __restrict__ accf,
    float* __restrict__ out_corw, const float* __restrict__ depth_hypo,
    float* __restrict__ out, int v, int b)
{
    int d = tid & 31;
    int p = tid >> 5;
    int w = p & 127, h = p >> 7;
    double cw, r;
    sample_view(d, p, w, h, ownbuf, tapbuf, grids, out_corw, v, b, cw, r);
    if (MODE == 0) {
        float2 a; a.x = (float)(1e-8 + cw); a.y = (float)(cw * r);
        accf[tid] = a;
    } else if (MODE == 1) {
        float2 a = accf[tid];
        a.x = (float)((double)a.x + cw);
        a.y = (float)((double)a.y + cw * r);
        accf[tid] = a;
    } else {
        float2 a = accf[tid];
        finalize_core(d, p, b, (double)a.x + cw, (double)a.y + cw * r, depth_hypo, out);
    }
}

__global__ __launch_bounds__(256) void warp_corr(
    const float* __restrict__ srcf, const float* __restrict__ reff,
    const float* __restrict__ dh, const double* __restrict__ projws,
    const double* __restrict__ wtab,
    float2* __restrict__ ownbuf, float2* __restrict__ tapbuf, int v, int b)
{
    __shared__ float sU1[Gn * Nn], sU2[Gn * Nn], sR[Gn];
    int lt = threadIdx.x;
    if (lt < Gn * Nn) { sU1[lt] = (float)wtab[8 + lt]; sU2[lt] = (float)wtab[40 + lt]; }
    if (lt < Gn) sR[lt] = (float)wtab[lt];
    __syncthreads();
    warp_body(blockIdx.x * 256 + lt, srcf, reff, dh, projws, sU1, sU2, sR,
              ownbuf, tapbuf, v, b);
}

template <int MODE>
__global__ __launch_bounds__(256) void sample_enh(
    const float2* __restrict__ ownbuf, const float2* __restrict__ tapbuf,
    const float* __restrict__ grids, float2* __restrict__ accf,
    float* __restrict__ out_corw, const float* __restrict__ depth_hypo,
    float* __restrict__ out, int v, int b)
{
    sample_body<MODE>(blockIdx.x * 256 + threadIdx.x, ownbuf, tapbuf, grids,
                      accf, out_corw, depth_hypo, out, v, b);
}

template <int MODE>
__global__ __launch_bounds__(256) void fused_sw(
    const float* __restrict__ srcf, const float* __restrict__ reff,
    const float* __restrict__ dh, const double* __restrict__ projws,
    const double* __restrict__ wtab, const float* __restrict__ grids,
    const float2* __restrict__ ownR, const float2* __restrict__ tapR,
    float2* __restrict__ ownW, float2* __restrict__ tapW,
    float2* __restrict__ accf, float* __restrict__ out_corw,
    float* __restrict__ out, int vs, int bs, int vw, int bw)
{
    int lt = threadIdx.x;
    int role = blockIdx.x & 1;
    int vb   = blockIdx.x >> 1;
    if (role == 0) {
        sample_body<MODE>(vb * 256 + lt, ownR, tapR, grids,
                          accf, out_corw, dh, out, vs, bs);
    } else {
        __shared__ float sU1[Gn * Nn], sU2[Gn * Nn], sR[Gn];
        if (lt < Gn * Nn) { sU1[lt] = (float)wtab[8 + lt]; sU2[lt] = (float)wtab[40 + lt]; }
        if (lt < Gn) sR[lt] = (float)wtab[lt];
        __syncthreads();
        warp_body(vb * 256 + lt, srcf, reff, dh, projws,
                  sU1, sU2, sR, ownW, tapW, vw, bw);
    }
}

// ---------------------------------------------------------------------------
extern "C" void kernel_launch(void* const* d_in, const int* in_sizes, int n_in,
                              void* d_out, int out_size, void* d_ws, size_t ws_size,
                              hipStream_t stream) {
    const float* reff  = (const float*)d_in[0];  // (V,B,C,H,W)
    const float* srcf  = (const float*)d_in[1];  // (V,B,C,H,W)
    const float* pm    = (const float*)d_in[2];  // (B,V+1,2,4,4)
    const float* dh    = (const float*)d_in[3];  // (B,D,H,W)
    const float* grids = (const float*)d_in[4];  // (V,B,N,H,W,2)
    const float* wreg  = (const float*)d_in[5];  // (G,)
    const float* wenh  = (const float*)d_in[6];  // (G,G*N)
    float* out = (float*)d_out;
    double* projws = (double*)d_ws;
    double* wtab   = (double*)((char*)d_ws + 1024);
    char*   base   = (char*)d_ws + 2048;
    // mega layout: tap_all [8][4*DHW] f2 (134.2MB) | own_all [8][DHW] f2 (33.6MB)
    //              | qs_all [8][Gn*HW] f4 (16.8MB) | qr_all (16.8MB)  => ~201.4MB
    float2* tap_all = (float2*)base;
    float2* own_all = tap_all + (size_t)NST * Nn * DHW;
    float4* qs_all  = (float4*)(own_all + (size_t)NST * DHW);
    float4* qr_all  = qs_all + (size_t)NST * Gn * HW;
    size_t need_mega = 2048 + (size_t)NST * Nn * DHW * 8 + (size_t)NST * DHW * 8
                     + 2 * (size_t)NST * Gn * HW * 16;
    // fallback layout (overlays same region):
    float2* accf = (float2*)base;
    float2* own0 = accf + DHW;
    float2* tap0 = own0 + DHW;
    float2* own1 = tap0 + (size_t)DHW * Nn;
    float2* tap1 = own1 + DHW;
    size_t need_pipe = 2048 + (size_t)DHW * 8 + 2 * ((size_t)DHW * 8 + (size_t)DHW * Nn * 8);

    setup_proj<<<1, 64, 0, stream>>>(pm, wenh, wreg, projws, wtab);
    float* out_corw = out + 2*BHW + BDHW;

    if (ws_size >= need_mega) {
        mega_repack<<<NST * RBLK, 256, 0, stream>>>(srcf, reff, qs_all, qr_all);
        mega_warp<<<NST * WBLK, 256, 0, stream>>>(qs_all, qr_all, dh, projws, wtab,
                                                  own_all, tap_all);
        mega_sample<<<BDHW / 256, 256, 0, stream>>>(own_all, tap_all, grids, dh,
                                                    out_corw, out);
    } else if (ws_size >= need_pipe) {
        float2* owns[2] = { own0, own1 };
        float2* taps[2] = { tap0, tap1 };
        warp_corr<<<NBLK, 256, 0, stream>>>(srcf, reff, dh, projws, wtab,
                                            own0, tap0, 0, 0);
        for (int k = 1; k < 8; k++) {
            int vs = (k - 1) & 3, bs = (k - 1) >> 2;
            int vw = k & 3,       bw = k >> 2;
            float2* oR = owns[(k - 1) & 1]; float2* tR = taps[(k - 1) & 1];
            float2* oW = owns[k & 1];       float2* tW = taps[k & 1];
            if (vs == 0)
                fused_sw<0><<<2*NBLK, 256, 0, stream>>>(srcf, reff, dh, projws, wtab, grids,
                                                        oR, tR, oW, tW, accf,
                                                        out_corw, out, vs, bs, vw, bw);
            else if (vs == 3)
                fused_sw<2><<<2*NBLK, 256, 0, stream>>>(srcf, reff, dh, projws, wtab, grids,
                                                        oR, tR, oW, tW, accf,
                                                        out_corw, out, vs, bs, vw, bw);
            else
                fused_sw<1><<<2*NBLK, 256, 0, stream>>>(srcf, reff, dh, projws, wtab, grids,
                                                        oR, tR, oW, tW, accf,
                                                        out_corw, out, vs, bs, vw, bw);
        }
        sample_enh<2><<<NBLK, 256, 0, stream>>>(owns[1], taps[1], grids, accf,
                                                out_corw, dh, out, 3, 1);
    } else {
        for (int b = 0; b < Bn; b++) {
            for (int v = 0; v < Vv; v++) {
                warp_corr<<<NBLK, 256, 0, stream>>>(srcf, reff, dh, projws, wtab,
                                                    own0, tap0, v, b);
                if (v == 0)
                    sample_enh<0><<<NBLK, 256, 0, stream>>>(own0, tap0, grids, accf,
                                                            out_corw, dh, out, v, b);
                else if (v < Vv - 1)
                    sample_enh<1><<<NBLK, 256, 0, stream>>>(own0, tap0, grids, accf,
                                                            out_corw, dh, out, v, b);
                else
                    sample_enh<2><<<NBLK, 256, 0, stream>>>(own0, tap0, grids, accf,
                                                            out_corw, dh, out, v, b);
            }
        }
    }
}